// Round 2
// baseline (1272.713 us; speedup 1.0000x reference)
//
#include <hip/hip_runtime.h>
#include <hip/hip_bf16.h>

// Shapes
#define NB   128
#define CIN  1024
#define HW   256      // 16*16
#define DIN  2048
#define LL   512
#define DOUT 1024
#define NQ   16

#define SC   16       // d-split for k_scores (per n-quarter)
#define NQTR 32       // n per quarter

typedef __attribute__((ext_vector_type(8))) short bf16x8;
typedef __attribute__((ext_vector_type(4))) float f32x4;

// K1: one wave per e; computes qT[e][qi] for all 16 qi.
__global__ __launch_bounds__(256) void k_q(const float* __restrict__ query,
                                           const float* __restrict__ Win,
                                           float* __restrict__ qT) {
  int e    = blockIdx.x * 4 + (threadIdx.x >> 6);   // 2048 waves
  int lane = threadIdx.x & 63;
  const float* wr = Win + (size_t)e * DIN;
  float acc[16];
  #pragma unroll
  for (int qi = 0; qi < 16; ++qi) acc[qi] = 0.f;
  #pragma unroll 2
  for (int d = lane; d < DIN; d += 64) {
    float w = wr[d];
    #pragma unroll
    for (int qi = 0; qi < 16; ++qi) acc[qi] += w * query[qi * DIN + d];
  }
  #pragma unroll
  for (int qi = 0; qi < 16; ++qi) {
    float a = acc[qi];
    #pragma unroll
    for (int m = 32; m; m >>= 1) a += __shfl_xor(a, m);
    if (lane == 0) qT[e * 16 + qi] = a;
  }
}

// K1b: bias[qi][o] = sum_e q[qi][e] * W_out[o][2048+e]  (fp32, one wave per o).
// This is the q-half of the combined GEMM — constant over n.
__global__ __launch_bounds__(256) void k_bias(const float* __restrict__ qT,
                                              const float* __restrict__ W,
                                              float* __restrict__ bias) {
  int o    = blockIdx.x * 4 + (threadIdx.x >> 6);   // 1024 waves
  int lane = threadIdx.x & 63;
  const float* wr = W + (size_t)o * (2 * DIN) + DIN;
  float acc[16];
  #pragma unroll
  for (int qi = 0; qi < 16; ++qi) acc[qi] = 0.f;
  for (int e = lane; e < DIN; e += 64) {
    float w = wr[e];
    #pragma unroll
    for (int qi = 0; qi < 16; ++qi) acc[qi] += w * qT[e * 16 + qi];
  }
  #pragma unroll
  for (int qi = 0; qi < 16; ++qi) {
    float a = acc[qi];
    #pragma unroll
    for (int m = 32; m; m >>= 1) a += __shfl_xor(a, m);
    if (lane == 0) bias[o * 16 + qi] = a;
  }
}

// Kw: W_out[:, 0:2048] fp32 -> bf16 [1024][2048]
__global__ __launch_bounds__(256) void k_wcast(const float* __restrict__ W,
                                               __hip_bfloat16* __restrict__ Wb) {
  int idx = blockIdx.x * 256 + threadIdx.x;          // 262144
  int o = idx >> 8, e0 = (idx & 255) * 8;
  const float* src = W + (size_t)o * (2 * DIN) + e0;
  union { bf16x8 v; __hip_bfloat16 h[8]; } u;
  #pragma unroll
  for (int j = 0; j < 8; ++j) u.h[j] = __float2bfloat16(src[j]);
  *(bf16x8*)&Wb[(size_t)o * DIN + e0] = u.v;
}

// K2: partial scores for one n-quarter. grid (bn=32, c=SC). 512 blocks, 2/CU.
__global__ __launch_bounds__(256) void k_scores(const float* __restrict__ ctx,
                                                const float* __restrict__ qT,
                                                float* __restrict__ part,
                                                int nbase) {
  int bn = blockIdx.x, c = blockIdx.y, t = threadIdx.x;
  int n = nbase + bn;
  const int DS = DIN / SC;                           // 128
  const float* cn  = ctx + (size_t)n * DIN * LL + (size_t)c * DS * LL;
  const float* qTc = qT + (size_t)c * DS * 16;
  float2 acc[16];
  #pragma unroll
  for (int qi = 0; qi < 16; ++qi) acc[qi] = make_float2(0.f, 0.f);
  #pragma unroll 8
  for (int d = 0; d < DS; ++d) {
    float2 v = *(const float2*)&cn[(size_t)d * LL + 2 * t];
    const float* qr = qTc + d * 16;
    #pragma unroll
    for (int qi = 0; qi < 16; ++qi) {
      acc[qi].x += qr[qi] * v.x;
      acc[qi].y += qr[qi] * v.y;
    }
  }
  float* po = part + (size_t)(c * NQTR + bn) * 16 * LL;
  #pragma unroll
  for (int qi = 0; qi < 16; ++qi)
    *(float2*)&po[qi * LL + 2 * t] = acc[qi];
}

// K3: reduce partials + softmax over l (one quarter). grid 512 = (bn, qi).
__global__ __launch_bounds__(256) void k_softmax(const float* __restrict__ part,
                                                 float* __restrict__ wT,
                                                 int nbase) {
  int b = blockIdx.x, bn = b >> 4, qi = b & 15, t = threadIdx.x;
  int n = nbase + bn;
  __shared__ float red[256];
  float sc0 = 0.f, sc1 = 0.f;
  #pragma unroll
  for (int c = 0; c < SC; ++c) {
    const float* p = part + ((size_t)(c * NQTR + bn) * 16 + qi) * LL;
    sc0 += p[t];
    sc1 += p[t + 256];
  }
  red[t] = fmaxf(sc0, sc1);
  __syncthreads();
  for (int s = 128; s; s >>= 1) { if (t < s) red[t] = fmaxf(red[t], red[t + s]); __syncthreads(); }
  float M = red[0];
  __syncthreads();
  float e0 = expf(sc0 - M), e1 = expf(sc1 - M);
  red[t] = e0 + e1;
  __syncthreads();
  for (int s = 128; s; s >>= 1) { if (t < s) red[t] += red[t + s]; __syncthreads(); }
  float inv = 1.0f / red[0];
  wT[((size_t)n * LL + t) * 16 + qi]       = e0 * inv;
  wT[((size_t)n * LL + t + 256) * 16 + qi] = e1 * inv;
}

// K4: mix for one n-quarter; ctx slice is LLC-hot from k_scores. grid (8, 32).
__global__ __launch_bounds__(256) void k_mix(const float* __restrict__ ctx,
                                             const float* __restrict__ wT,
                                             __hip_bfloat16* __restrict__ comb,
                                             int nbase) {
  int dt = blockIdx.x, n = nbase + blockIdx.y, t = threadIdx.x;
  int dbase = dt * 256;
  __shared__ float tile[256 * 33];
  const float* cn = ctx + (size_t)n * DIN * LL;
  const float* wn = wT + (size_t)n * LL * 16;
  const float* src0 = cn + (size_t)dbase * LL;
  float acc[16];
  #pragma unroll
  for (int qi = 0; qi < 16; ++qi) acc[qi] = 0.f;

  int lq = (t & 7) * 4;
  int row0 = t >> 3;

  float4 g[8];
  #pragma unroll
  for (int p = 0; p < 8; ++p)
    g[p] = *(const float4*)&src0[(size_t)(row0 + p * 32) * LL + lq];

  for (int ch = 0; ch < 16; ++ch) {
    __syncthreads();
    #pragma unroll
    for (int p = 0; p < 8; ++p) {
      int row = row0 + p * 32;
      float* dst = &tile[row * 33 + lq];
      dst[0] = g[p].x; dst[1] = g[p].y; dst[2] = g[p].z; dst[3] = g[p].w;
    }
    __syncthreads();
    if (ch < 15) {
      int l0n = (ch + 1) * 32;
      #pragma unroll
      for (int p = 0; p < 8; ++p)
        g[p] = *(const float4*)&src0[(size_t)(row0 + p * 32) * LL + l0n + lq];
    }
    int l0 = ch * 32;
    for (int l = 0; l < 32; ++l) {
      float v = tile[t * 33 + l];
      const float* wr = wn + (size_t)(l0 + l) * 16;   // wave-uniform -> s_load
      #pragma unroll
      for (int qi = 0; qi < 16; ++qi) acc[qi] += wr[qi] * v;
    }
  }
  #pragma unroll
  for (int qi = 0; qi < 16; ++qi)
    comb[(size_t)(n * 16 + qi) * DIN + dbase + t] = __float2bfloat16(acc[qi]);
}

// K5: out_small = tanh(mix @ Wb^T + bias) with fused nearest-upsample write.
// A [2048][2048] bf16, B [1024][2048] bf16, K-step 64, reg-prefetched staging.
__global__ __launch_bounds__(256) void k_gemm(const __hip_bfloat16* __restrict__ A,
                                              const __hip_bfloat16* __restrict__ B,
                                              const float* __restrict__ bias,
                                              float* __restrict__ out) {
  __shared__ short la[64 * 72];
  __shared__ short lb[64 * 72];
  int t = threadIdx.x, lane = t & 63, wid = t >> 6;
  int m0 = blockIdx.y * 64, o0 = blockIdx.x * 64;
  int wy = wid >> 1, wx = wid & 1;
  f32x4 acc[2][2] = {};
  int srow = t >> 2, sq = (t & 3) * 16;   // 4 threads/row, 16 shorts each
  const short* As = (const short*)A;
  const short* Bs = (const short*)B;

  float4 ga0 = *(const float4*)&As[(size_t)(m0 + srow) * DIN + sq];
  float4 ga1 = *(const float4*)&As[(size_t)(m0 + srow) * DIN + sq + 8];
  float4 gb0 = *(const float4*)&Bs[(size_t)(o0 + srow) * DIN + sq];
  float4 gb1 = *(const float4*)&Bs[(size_t)(o0 + srow) * DIN + sq + 8];

  for (int kc = 0; kc < DIN; kc += 64) {
    __syncthreads();
    *(float4*)&la[srow * 72 + sq]     = ga0;
    *(float4*)&la[srow * 72 + sq + 8] = ga1;
    *(float4*)&lb[srow * 72 + sq]     = gb0;
    *(float4*)&lb[srow * 72 + sq + 8] = gb1;
    __syncthreads();
    if (kc + 64 < DIN) {
      ga0 = *(const float4*)&As[(size_t)(m0 + srow) * DIN + kc + 64 + sq];
      ga1 = *(const float4*)&As[(size_t)(m0 + srow) * DIN + kc + 64 + sq + 8];
      gb0 = *(const float4*)&Bs[(size_t)(o0 + srow) * DIN + kc + 64 + sq];
      gb1 = *(const float4*)&Bs[(size_t)(o0 + srow) * DIN + kc + 64 + sq + 8];
    }
    int fr = lane & 15, fq = (lane >> 4) * 8;
    #pragma unroll
    for (int kk = 0; kk < 64; kk += 32) {
      bf16x8 a0 = *(const bf16x8*)&la[(wy * 32 + fr) * 72 + kk + fq];
      bf16x8 a1 = *(const bf16x8*)&la[(wy * 32 + 16 + fr) * 72 + kk + fq];
      bf16x8 b0 = *(const bf16x8*)&lb[(wx * 32 + fr) * 72 + kk + fq];
      bf16x8 b1 = *(const bf16x8*)&lb[(wx * 32 + 16 + fr) * 72 + kk + fq];
      acc[0][0] = __builtin_amdgcn_mfma_f32_16x16x32_bf16(a0, b0, acc[0][0], 0, 0, 0);
      acc[0][1] = __builtin_amdgcn_mfma_f32_16x16x32_bf16(a0, b1, acc[0][1], 0, 0, 0);
      acc[1][0] = __builtin_amdgcn_mfma_f32_16x16x32_bf16(a1, b0, acc[1][0], 0, 0, 0);
      acc[1][1] = __builtin_amdgcn_mfma_f32_16x16x32_bf16(a1, b1, acc[1][1], 0, 0, 0);
    }
  }

  int col = lane & 15, rbase = (lane >> 4) * 4;
  #pragma unroll
  for (int si = 0; si < 2; ++si)
    #pragma unroll
    for (int sj = 0; sj < 2; ++sj)
      #pragma unroll
      for (int r = 0; r < 4; ++r) {
        int m = m0 + wy * 32 + si * 16 + rbase + r;
        int o = o0 + wx * 32 + sj * 16 + col;
        int n = m >> 4, qi = m & 15;
        float v = tanhf(acc[si][sj][r] + bias[o * 16 + qi]);
        float* op = out + (size_t)(n * 2048 + CIN + o) * HW
                        + ((qi >> 2) * 4) * 16 + (qi & 3) * 4;
        float4 vv = make_float4(v, v, v, v);
        *(float4*)&op[0]  = vv;
        *(float4*)&op[16] = vv;
        *(float4*)&op[32] = vv;
        *(float4*)&op[48] = vv;
      }
}

// K6: copy cat_tensor into channels [0,1024)
__global__ __launch_bounds__(256) void k_copy(const float* __restrict__ cat,
                                              float* __restrict__ out) {
  size_t idx = (size_t)blockIdx.x * 256 + threadIdx.x;  // float4 index
  int n = (int)(idx >> 16);
  int rem = (int)(idx & 65535);
  const float4* c4 = (const float4*)cat;
  float4* o4 = (float4*)out;
  o4[(size_t)n * 131072 + rem] = c4[idx];
}

extern "C" void kernel_launch(void* const* d_in, const int* in_sizes, int n_in,
                              void* d_out, int out_size, void* d_ws, size_t ws_size,
                              hipStream_t stream) {
  const float* cat   = (const float*)d_in[0];
  const float* ctx   = (const float*)d_in[1];
  const float* query = (const float*)d_in[2];
  const float* W_in  = (const float*)d_in[3];
  const float* W_out = (const float*)d_in[4];
  float* out = (float*)d_out;

  // workspace: qT 128K | wT 4M | part 16M | bias 64K | Wb 4M | comb 8M  (~32.3MB)
  float* qT   = (float*)d_ws;                          // 32768 f
  float* wT   = qT + 32768;                            // 1048576 f
  float* part = wT + 1048576;                          // 4194304 f (SC*32*16*512)
  float* bias = part + 4194304;                        // 16384 f
  __hip_bfloat16* Wb   = (__hip_bfloat16*)(bias + 16384);   // 2097152 bf16
  __hip_bfloat16* comb = Wb + 2097152;                       // 4194304 bf16

  // independent prep first; k_copy's 256MB stream runs before ctx enters LLC
  k_copy  <<<32768, 256, 0, stream>>>(cat, out);
  k_q     <<<512, 256, 0, stream>>>(query, W_in, qT);
  k_wcast <<<1024, 256, 0, stream>>>(W_out, Wb);
  k_bias  <<<256, 256, 0, stream>>>(qT, W_out, bias);

  // LLC-blocked attention: per 32-n quarter, ctx slice (128MB) stays cache-hot
  // between the scores read and the mix re-read.
  for (int q = 0; q < 4; ++q) {
    int nbase = q * NQTR;
    k_scores <<<dim3(NQTR, SC), 256, 0, stream>>>(ctx, qT, part, nbase);
    k_softmax<<<NQTR * 16, 256, 0, stream>>>(part, wT, nbase);
    k_mix    <<<dim3(8, NQTR), 256, 0, stream>>>(ctx, wT, comb, nbase);
  }

  k_gemm <<<dim3(16, 32), 256, 0, stream>>>(comb, Wb, bias, out);
}